// Round 11
// baseline (39.818 us; speedup 1.0000x reference)
//
#include <hip/hip_runtime.h>

#define TT 256
#define HH 512
#define WW 512
#define LOG2E 1.44269504088896340736f
#define KS (100.0f * LOG2E)
#define STEP (1.0f / 511.0f)
#define TROWS 16

typedef _Float16 half8 __attribute__((ext_vector_type(8)));
typedef float f32x4v __attribute__((ext_vector_type(4)));

// One fused kernel. Block = 16-px-wide x 16-row tile, 8 waves.
// Wave w owns K-slice: triangles [w*32, w*32+32).
// Lane l: px = l&15, slot = l>>4; lane time-shares 8 triangles
//   t = w*32 + slot*8 + c (c=0..7) == the MFMA k-slot (l>>4)*8+c.
// Per y-step: u-advance (24 mul) -> P (32) -> 2x batch-4 rcp -> f16 pack ->
//   one mfma_f32_16x16x32_f16: D[ch][px] = sum_k A[ch][k] * w[k][px].
// A rows 0-3 = {expd, expd*cr, expd*cg, expd*cb}, rows 4-15 zero.
// D (lanes 0-15, regs 0-3) = float4 per pixel -> per-wave LDS region,
// cross-wave sum + eps baseline + normalize in epilogue.
__global__ __launch_bounds__(512, 6) void tri_render(
        const float* __restrict__ verts,
        const float* __restrict__ colors,
        const float* __restrict__ depth,
        float* __restrict__ out)
{
    __shared__ float4 s_q[TT][3];             // 12 KiB edge consts
    __shared__ _Float16 s_colA[TT][4];        // 2 KiB  {ce,ecr,ecg,ecb}
    __shared__ float4 s_eps[TT];              // 4 KiB
    __shared__ float4 s_out[8][TROWS][16];    // 32 KiB  (50 KiB total)

    int tid  = threadIdx.x;
    int lane = tid & 63;
    int wave = __builtin_amdgcn_readfirstlane(tid >> 6);

    // ---------- phase 1: records ----------
    if (tid < TT) {
        int t = tid;
        float v0x = verts[t*6+0], v0y = verts[t*6+1];
        float v1x = verts[t*6+2], v1y = verts[t*6+3];
        float v2x = verts[t*6+4], v2y = verts[t*6+5];
        float dx0 = v1x-v0x, dy0 = v1y-v0y;
        float dx1 = v2x-v1x, dy1 = v2y-v1y;
        float dx2 = v0x-v2x, dy2 = v0y-v2y;
        float c0 = v0y*dx0 - v0x*dy0;
        float c1 = v1y*dx1 - v1x*dy1;
        float c2 = v2y*dx2 - v2x*dy2;
        float expd = __builtin_amdgcn_exp2f(depth[t]*LOG2E);
        float cr = colors[t*3+0], cg = colors[t*3+1], cb = colors[t*3+2];
        s_q[t][0] = make_float4(KS*dy0, KS*dx0, KS*c0, KS*dy1);
        s_q[t][1] = make_float4(KS*dx1, KS*c1, KS*dy2, KS*dx2);
        s_q[t][2] = make_float4(KS*c2,
                __builtin_amdgcn_exp2f(STEP*(KS*dx0)),
                __builtin_amdgcn_exp2f(STEP*(KS*dx1)),
                __builtin_amdgcn_exp2f(STEP*(KS*dx2)));
        s_colA[t][0] = (_Float16)expd;
        s_colA[t][1] = (_Float16)(expd*cr);
        s_colA[t][2] = (_Float16)(expd*cg);
        s_colA[t][3] = (_Float16)(expd*cb);
        float se = expd * 1e-6f;
        s_eps[t] = make_float4(se, se*cr, se*cg, se*cb);
    }
    __syncthreads();

    // ---------- eps baseline (per-wave shuffle reduce, deterministic) ----------
    float4 e0 = s_eps[lane],     e1 = s_eps[lane+64];
    float4 e2 = s_eps[lane+128], e3 = s_eps[lane+192];
    float b0 = (e0.x+e1.x)+(e2.x+e3.x);
    float b1 = (e0.y+e1.y)+(e2.y+e3.y);
    float b2 = (e0.z+e1.z)+(e2.z+e3.z);
    float b3 = (e0.w+e1.w)+(e2.w+e3.w);
    #pragma unroll
    for (int d = 1; d < 64; d <<= 1) {
        b0 += __shfl_xor(b0, d, 64);
        b1 += __shfl_xor(b1, d, 64);
        b2 += __shfl_xor(b2, d, 64);
        b3 += __shfl_xor(b3, d, 64);
    }

    // ---------- init per-lane triangle state ----------
    int bx = blockIdx.x & 31;       // 32 x-tiles of 16
    int by = blockIdx.x >> 5;       // 32 y-tiles of 16
    int px16 = lane & 15;
    int slot = lane >> 4;
    int tb = wave * 32 + slot * 8;

    float x   = (float)(bx*16 + px16) * STEP;
    float py0 = (float)(by*TROWS) * STEP;

    float u0[8], u1[8], u2[8], k0[8], k1[8], k2[8];
    #pragma unroll
    for (int c = 0; c < 8; ++c) {
        float4 q0 = s_q[tb+c][0];
        float4 q1 = s_q[tb+c][1];
        float4 q2 = s_q[tb+c][2];
        // n = -E = py*Dx - px*Dy - C  (same formulation as validated R8)
        float n0 = fmaf(py0, q0.y, -q0.z); n0 = fmaf(-x, q0.x, n0);
        float n1 = fmaf(py0, q1.x, -q1.y); n1 = fmaf(-x, q0.w, n1);
        float n2 = fmaf(py0, q1.w, -q2.x); n2 = fmaf(-x, q1.z, n2);
        u0[c] = __builtin_amdgcn_exp2f(n0);
        u1[c] = __builtin_amdgcn_exp2f(n1);
        u2[c] = __builtin_amdgcn_exp2f(n2);
        k0[c] = q2.y; k1[c] = q2.z; k2[c] = q2.w;
    }

    // A fragment: lane holds A[m = lane&15][k = slot*8 + j]; rows >=4 zero.
    half8 af = {};
    if (px16 < 4) {
        #pragma unroll
        for (int j = 0; j < 8; ++j)
            af[j] = s_colA[tb + j][px16];
    }

    const f32x4v zero = {0.0f, 0.0f, 0.0f, 0.0f};

    // ---------- y-loop ----------
    #pragma unroll 1
    for (int y = 0; y < TROWS; ++y) {
        float P[8];
        #pragma unroll
        for (int c = 0; c < 8; ++c) {
            float a = u1[c] + 1.0f;
            float p = fmaf(u0[c], a, a);     // (1+u0)(1+u1)
            p = fmaf(u2[c], p, p);           // *(1+u2)
            // clamp 2^31 (batch-4 product <= 2^124); v_min also rescues
            // the fma(0,inf,inf)=NaN case (returns the non-NaN operand).
            P[c] = fminf(p, 2147483648.0f);
            u0[c] *= k0[c]; u1[c] *= k1[c]; u2[c] *= k2[c];  // advance row
        }
        float w[8];
        {   // batch-4 reciprocal, triangles 0..3
            float pp1 = P[0]*P[1], pp2 = pp1*P[2], pp3 = pp2*P[3];
            float inv = __builtin_amdgcn_rcpf(pp3);
            w[3] = inv*pp2; inv *= P[3];
            w[2] = inv*pp1; inv *= P[2];
            w[1] = inv*P[0];
            w[0] = inv*P[1];
        }
        {   // batch-4 reciprocal, triangles 4..7
            float pp1 = P[4]*P[5], pp2 = pp1*P[6], pp3 = pp2*P[7];
            float inv = __builtin_amdgcn_rcpf(pp3);
            w[7] = inv*pp2; inv *= P[7];
            w[6] = inv*pp1; inv *= P[6];
            w[5] = inv*P[4];
            w[4] = inv*P[5];
        }
        half8 wf;
        #pragma unroll
        for (int c = 0; c < 8; ++c) wf[c] = (_Float16)w[c];

        f32x4v D = __builtin_amdgcn_mfma_f32_16x16x32_f16(af, wf, zero, 0, 0, 0);
        // D: col = lane&15 (pixel), row = (lane>>4)*4 + reg (channel for
        // lanes 0-15, zero rows elsewhere)
        if (lane < 16)
            s_out[wave][y][lane] = make_float4(D[0], D[1], D[2], D[3]);
    }
    __syncthreads();

    // ---------- epilogue: 256 threads -> 256 pixels ----------
    if (tid < 16 * TROWS) {
        int yy = tid >> 4, p = tid & 15;
        float4 a0 = s_out[0][yy][p], a1 = s_out[1][yy][p];
        float4 a2 = s_out[2][yy][p], a3 = s_out[3][yy][p];
        float4 a4 = s_out[4][yy][p], a5 = s_out[5][yy][p];
        float4 a6 = s_out[6][yy][p], a7 = s_out[7][yy][p];
        float sum = b0 + (((a0.x+a1.x)+(a2.x+a3.x)) + ((a4.x+a5.x)+(a6.x+a7.x)));
        float r   = b1 + (((a0.y+a1.y)+(a2.y+a3.y)) + ((a4.y+a5.y)+(a6.y+a7.y)));
        float g   = b2 + (((a0.z+a1.z)+(a2.z+a3.z)) + ((a4.z+a5.z)+(a6.z+a7.z)));
        float bb  = b3 + (((a0.w+a1.w)+(a2.w+a3.w)) + ((a4.w+a5.w)+(a6.w+a7.w)));
        float inv = 1.0f / sum;
        int gy = by*TROWS + yy;
        int gx = bx*16 + p;
        int pix = gy*WW + gx;
        out[pix]           = r  * inv;
        out[HH*WW + pix]   = g  * inv;
        out[2*HH*WW + pix] = bb * inv;
    }
}

extern "C" void kernel_launch(void* const* d_in, const int* in_sizes, int n_in,
                              void* d_out, int out_size, void* d_ws, size_t ws_size,
                              hipStream_t stream) {
    const float* verts  = (const float*)d_in[0];
    const float* colors = (const float*)d_in[1];
    const float* depth  = (const float*)d_in[2];
    float* out = (float*)d_out;

    tri_render<<<dim3((WW/16) * (HH/TROWS)), dim3(512), 0, stream>>>(
        verts, colors, depth, out);
}

// Round 16
// 32.101 us; speedup vs baseline: 1.2404x; 1.2404x over previous
//
#include <hip/hip_runtime.h>

#define TT 256
#define HH 512
#define WW 512
#define LOG2E 1.44269504088896340736f
#define KS (100.0f * LOG2E)
#define STEP (1.0f / 511.0f)
#define RUN 4      // consecutive y-pixels per thread
#define CHUNK 32   // triangles per wave (8 waves cover all 256)

// Fused single kernel (R8 lineage + R10 batch-rcp + LDS-read software pipeline).
//  phase 1: threads 0..255 build triangle records into LDS
//    rec[t] = {Dy0,Dx0,C0,Dy1} {Dx1,C1,Dy2,Dx2} {C2,k0,k1,k2} {ce,cr,cg,cb}
//    (edge consts pre-scaled by SHARPNESS*log2e; ce=expd, c*=expd*color)
//  phase 2: per-wave shuffle reduction of rec[.][3]; baseline = 1e-6 * sum
//  phase 3: each wave accumulates its 32 triangles over the 64x4 tile.
//    Record reads are 2-stage pipelined: q0/q1/q2 prefetched one triangle
//    ahead; q3 (colors) loaded at iteration top, consumed at the end --
//    hides the ~120-cyc LDS latency that capped R8 at ~53% issue efficiency.
//  phase 4: two-stage LDS reduction across 8 waves, finalize 256 pixels
__global__ __launch_bounds__(512, 8) void tri_render(
        const float* __restrict__ verts,
        const float* __restrict__ colors,
        const float* __restrict__ depth,
        float* __restrict__ out) {
    __shared__ float4 s_rec[TT][4];          // 16 KiB
    __shared__ float4 s_part[4][RUN][64];    // 16 KiB   (32 KiB total)

    int tid  = threadIdx.x;
    int lane = tid & 63;
    int wave = __builtin_amdgcn_readfirstlane(tid >> 6);

    // ---------- phase 1: build records ----------
    if (tid < TT) {
        int t = tid;
        float v0x = verts[t * 6 + 0], v0y = verts[t * 6 + 1];
        float v1x = verts[t * 6 + 2], v1y = verts[t * 6 + 3];
        float v2x = verts[t * 6 + 4], v2y = verts[t * 6 + 5];

        float dx0 = v1x - v0x, dy0 = v1y - v0y;
        float dx1 = v2x - v1x, dy1 = v2y - v1y;
        float dx2 = v0x - v2x, dy2 = v0y - v2y;
        float c0 = v0y * dx0 - v0x * dy0;
        float c1 = v1y * dx1 - v1x * dy1;
        float c2 = v2y * dx2 - v2x * dy2;

        float expd = __builtin_amdgcn_exp2f(depth[t] * LOG2E);
        float cr = colors[t * 3 + 0], cg = colors[t * 3 + 1], cb = colors[t * 3 + 2];

        s_rec[t][0] = make_float4(KS * dy0, KS * dx0, KS * c0, KS * dy1);
        s_rec[t][1] = make_float4(KS * dx1, KS * c1, KS * dy2, KS * dx2);
        s_rec[t][2] = make_float4(KS * c2,
                                  __builtin_amdgcn_exp2f(STEP * (KS * dx0)),
                                  __builtin_amdgcn_exp2f(STEP * (KS * dx1)),
                                  __builtin_amdgcn_exp2f(STEP * (KS * dx2)));
        s_rec[t][3] = make_float4(expd, expd * cr, expd * cg, expd * cb);
    }
    __syncthreads();

    // ---------- phase 2: eps baseline = 1e-6 * sum_t rec[t][3] ----------
    float4 e0 = s_rec[lane][3];
    float4 e1 = s_rec[lane + 64][3];
    float4 e2 = s_rec[lane + 128][3];
    float4 e3 = s_rec[lane + 192][3];
    float b0 = (e0.x + e1.x) + (e2.x + e3.x);
    float b1 = (e0.y + e1.y) + (e2.y + e3.y);
    float b2 = (e0.z + e1.z) + (e2.z + e3.z);
    float b3 = (e0.w + e1.w) + (e2.w + e3.w);
    #pragma unroll
    for (int d = 1; d < 64; d <<= 1) {
        b0 += __shfl_xor(b0, d, 64);
        b1 += __shfl_xor(b1, d, 64);
        b2 += __shfl_xor(b2, d, 64);
        b3 += __shfl_xor(b3, d, 64);
    }
    b0 *= 1e-6f; b1 *= 1e-6f; b2 *= 1e-6f; b3 *= 1e-6f;

    // ---------- phase 3: main accumulation ----------
    int bx = blockIdx.x & 7;    // 8 x-strips of 64
    int by = blockIdx.x >> 3;   // 128 y-runs of 4

    float px  = (float)(bx * 64 + lane) * STEP;
    float py0 = (float)(by * RUN) * STEP;

    float acc[RUN][4];
    #pragma unroll
    for (int i = 0; i < RUN; ++i) {
        acc[i][0] = 0.0f; acc[i][1] = 0.0f; acc[i][2] = 0.0f; acc[i][3] = 0.0f;
    }

    const float4* rec = &s_rec[wave * CHUNK][0];

    // prefetch triangle 0's edge records
    float4 p0 = rec[0];
    float4 p1 = rec[1];
    float4 p2 = rec[2];

    #pragma unroll 1
    for (int j = 0; j < CHUNK; ++j) {
        float4 c0 = p0, c1 = p1, c2 = p2;
        float4 c3 = rec[j * 4 + 3];          // colors: used only at the end
        int jn = (j + 1) & (CHUNK - 1);      // wraps on last iter (harmless)
        p0 = rec[jn * 4 + 0];                // prefetch next triangle
        p1 = rec[jn * 4 + 1];
        p2 = rec[jn * 4 + 2];

        // u_i = 2^(n_i); n = -E = py*Dx - px*Dy - C
        float n0 = fmaf(py0, c0.y, -c0.z);  n0 = fmaf(-px, c0.x, n0);
        float n1 = fmaf(py0, c1.x, -c1.y);  n1 = fmaf(-px, c0.w, n1);
        float n2 = fmaf(py0, c1.w, -c2.x);  n2 = fmaf(-px, c1.z, n2);
        float u0 = __builtin_amdgcn_exp2f(n0);
        float u1 = __builtin_amdgcn_exp2f(n1);
        float u2 = __builtin_amdgcn_exp2f(n2);
        float k0 = c2.y, k1 = c2.z, k2 = c2.w;

        // P per row, clamped to 2^31 so the 4-product <= 2^124 (finite).
        // fminf also rescues fma(0,inf,inf)=NaN (picks the clamp). R10-proven.
        float P[RUN];
        #pragma unroll
        for (int i = 0; i < RUN; ++i) {
            float a = u1 + 1.0f;
            float p = fmaf(u0, a, a);       // (1+u0)(1+u1)
            p = fmaf(u2, p, p);             // *(1+u2)
            P[i] = fminf(p, 2147483648.0f); // 2^31
            if (i != RUN - 1) { u0 *= k0; u1 *= k1; u2 *= k2; }
        }

        // batch-4 reciprocal: 1 rcp + 9 mul -> masks w_i = 1/P_i
        float t01   = P[0] * P[1];
        float t012  = t01  * P[2];
        float t0123 = t012 * P[3];
        float inv   = __builtin_amdgcn_rcpf(t0123);
        float w3   = inv  * t012;           // 1/P3
        float inv2 = inv  * P[3];           // 1/(P0 P1 P2)
        float w2   = inv2 * t01;            // 1/P2
        float inv3 = inv2 * P[2];           // 1/(P0 P1)
        float w1   = inv3 * P[0];           // 1/P1
        float w0   = inv3 * P[1];           // 1/P0

        float ce = c3.x, cr = c3.y, cg = c3.z, cb = c3.w;
        acc[0][0] = fmaf(w0, ce, acc[0][0]);
        acc[0][1] = fmaf(w0, cr, acc[0][1]);
        acc[0][2] = fmaf(w0, cg, acc[0][2]);
        acc[0][3] = fmaf(w0, cb, acc[0][3]);
        acc[1][0] = fmaf(w1, ce, acc[1][0]);
        acc[1][1] = fmaf(w1, cr, acc[1][1]);
        acc[1][2] = fmaf(w1, cg, acc[1][2]);
        acc[1][3] = fmaf(w1, cb, acc[1][3]);
        acc[2][0] = fmaf(w2, ce, acc[2][0]);
        acc[2][1] = fmaf(w2, cr, acc[2][1]);
        acc[2][2] = fmaf(w2, cg, acc[2][2]);
        acc[2][3] = fmaf(w2, cb, acc[2][3]);
        acc[3][0] = fmaf(w3, ce, acc[3][0]);
        acc[3][1] = fmaf(w3, cr, acc[3][1]);
        acc[3][2] = fmaf(w3, cg, acc[3][2]);
        acc[3][3] = fmaf(w3, cb, acc[3][3]);
    }
    __syncthreads();

    // ---------- phase 4: two-stage reduction across the 8 waves ----------
    if (wave >= 4) {
        #pragma unroll
        for (int i = 0; i < RUN; ++i)
            s_part[wave - 4][i][lane] =
                make_float4(acc[i][0], acc[i][1], acc[i][2], acc[i][3]);
    }
    __syncthreads();
    if (wave < 4) {
        #pragma unroll
        for (int i = 0; i < RUN; ++i) {
            float4 v = s_part[wave][i][lane];
            v.x += acc[i][0]; v.y += acc[i][1];
            v.z += acc[i][2]; v.w += acc[i][3];
            s_part[wave][i][lane] = v;
        }
    }
    __syncthreads();

    // finalize: first 256 threads -> 256 pixels (64 x 4 tile)
    if (tid < 64 * RUN) {
        int i = tid >> 6, l = tid & 63;
        float4 v0 = s_part[0][i][l];
        float4 v1 = s_part[1][i][l];
        float4 v2 = s_part[2][i][l];
        float4 v3 = s_part[3][i][l];
        float sum = b0 + ((v0.x + v1.x) + (v2.x + v3.x));
        float r   = b1 + ((v0.y + v1.y) + (v2.y + v3.y));
        float g   = b2 + ((v0.z + v1.z) + (v2.z + v3.z));
        float bch = b3 + ((v0.w + v1.w) + (v2.w + v3.w));
        float inv = 1.0f / sum;
        int gy = by * RUN + i;
        int gx = bx * 64 + l;
        int pix = gy * WW + gx;
        out[pix]               = r   * inv;
        out[HH * WW + pix]     = g   * inv;
        out[2 * HH * WW + pix] = bch * inv;
    }
}

extern "C" void kernel_launch(void* const* d_in, const int* in_sizes, int n_in,
                              void* d_out, int out_size, void* d_ws, size_t ws_size,
                              hipStream_t stream) {
    const float* verts  = (const float*)d_in[0];
    const float* colors = (const float*)d_in[1];
    const float* depth  = (const float*)d_in[2];
    float* out = (float*)d_out;

    tri_render<<<dim3((WW / 64) * (HH / RUN)), dim3(512), 0, stream>>>(
        verts, colors, depth, out);
}